// Round 13
// baseline (11479.889 us; speedup 1.0000x reference)
//
#include <hip/hip_runtime.h>
#include <hip/hip_bf16.h>
#include <math.h>

#define BB 512
#define HH 512
#define TT 1024

typedef __bf16 bf16;
typedef __bf16 bf16x8 __attribute__((ext_vector_type(8)));
typedef float f32x4 __attribute__((ext_vector_type(4)));
typedef unsigned long long ull;
typedef ull ull2 __attribute__((ext_vector_type(2)));

#define SENT 0x7FC07FC07FC07FC0ULL   // 4x bf16 NaN — h = so*tanh(c) is never NaN

// ---------------- ws layout (bytes) ----------------
// WcT : [2048][512] bf16 @ 0      (2 MB)  folded: Whh + Wfc ⊗ Wih
// biasC: [2048] f32      @ 2 MB   (8 KB)
// hb0/1/2: [512][512] bf16 rotating h buffers (3 x 512 KB)
#define WT_OFF 0
#define BC_OFF (2*1024*1024)
#define H0_OFF (BC_OFF + 8192)

__global__ void prep_weights(const float* __restrict__ Whh, const float* __restrict__ Wih,
                             const float* __restrict__ bih, const float* __restrict__ bhh,
                             const float* __restrict__ Wfc, const float* __restrict__ bfc,
                             bf16* __restrict__ WcT, float* __restrict__ biasC) {
    int col = blockIdx.x;                 // 0..2047
    float wih = Wih[col];
    for (int k = threadIdx.x; k < HH; k += blockDim.x)
        WcT[col * HH + k] = (bf16)(Whh[col * HH + k] + Wfc[k] * wih);
    if (threadIdx.x == 0) biasC[col] = bih[col] + bhh[col] + bfc[0] * wih;
}

__global__ void prep_state(const float* __restrict__ h, bf16* __restrict__ h0buf,
                           unsigned short* __restrict__ h1buf,
                           unsigned short* __restrict__ h2buf) {
    int i = blockIdx.x * blockDim.x + threadIdx.x;
    if (i < BB * HH) {
        h0buf[i] = (bf16)h[i];
        h1buf[i] = 0x7FC0;    // sentinel
        h2buf[i] = 0x7FC0;
    }
}

__device__ __forceinline__ float tanh_fast(float x) {
    float ax = fabsf(x);
    float e = __expf(-2.f * ax);
    float r = (1.f - e) / (1.f + e);
    return copysignf(r, x);
}
__device__ __forceinline__ float sigmoid_fast(float x) {
    return 1.f / (1.f + __expf(-x));
}
__device__ __forceinline__ bool has_sent(ull v) {
    ull y = v ^ SENT;
    return ((y - 0x0001000100010001ULL) & ~y & 0x8000800080008000ULL) != 0ULL;
}
__device__ __forceinline__ bool has_sent2(ull2 v) {
    return has_sent(v.x) | has_sent(v.y);
}

// Persistent LSTM, SINGLE-WAVE workgroups (64 thr), barrier-free main loop.
// 512 waves: wave (bt, wv16) owns batch rows bt*32..+32, hidden cols
// wv16*16..+16 (all 4 gates; gate-major MFMA N-tiles => pointwise is fully
// lane-local, no shfl). Exchange = round-9-proven MALL protocol (sc0 sc1,
// NaN-sentinel, 3 rotating buffers, clear-behind; store->clear ordering via
// the staging sweeps' vmcnt(0), wave-internal). Waves free-run: staging all
// of A_s proves every producer of h_s finished READING h_{s-1} (each stages
// the full tile before computing), so clearing buf[(s+2)%3] is safe — the
// r5 invariant, re-derived for 32-wave groups, no barriers anywhere.
__global__ __launch_bounds__(64, 1) void lstm_persist(
    const bf16* __restrict__ WcT,     // [2048][512] bf16 (folded)
    const float* __restrict__ biasC,  // [2048]
    const float* __restrict__ Wih,    // [2048]
    const float* __restrict__ Wfc,    // [512]
    const float* __restrict__ bfc,    // [1]
    const float* __restrict__ c0,     // [512*512] f32
    char* __restrict__ hbase,         // 3 x 512KB rotating buffers
    float* __restrict__ out)          // [512][1024]
{
    __shared__ __align__(16) bf16 Alds[32 * 512];  // XOR-swizzled h tile (32 KB)
    __shared__ float xls[32];                      // step-0 correction per row
    __shared__ float WfcLDS[512];
    __shared__ bf16 hrep[32][16];                  // h repack (32 B rows)

    const int lane = threadIdx.x;             // 0..63 (one wave)
    const int l15  = lane & 15;
    const int hi   = lane >> 4;
    const int bt   = blockIdx.x & 15;         // batch tile 0..15
    const int wv16 = blockIdx.x >> 4;         // hidden-16 block 0..31

    #pragma unroll
    for (int u = 0; u < 8; ++u) WfcLDS[u * 64 + lane] = Wfc[u * 64 + lane];

    // ---- weights: 4 gates x 16 cols -> 256 VGPRs/lane ----
    bf16x8 breg[4][16];
    float biasr[4], wihr[4];
    #pragma unroll
    for (int g = 0; g < 4; ++g) {
        int gcol = g * HH + wv16 * 16 + l15;
        const bf16* wp = WcT + (size_t)gcol * HH + hi * 8;
        #pragma unroll
        for (int kk = 0; kk < 16; ++kk)
            breg[g][kk] = *(const bf16x8*)(wp + kk * 32);
        biasr[g] = biasC[gcol];
        wihr[g]  = Wih[gcol];
    }

    const int jloc = wv16 * 16 + l15;         // my hidden col
    float creg[2][4];
    #pragma unroll
    for (int mt = 0; mt < 2; ++mt)
        #pragma unroll
        for (int r = 0; r < 4; ++r)
            creg[mt][r] = c0[(size_t)(bt * 32 + mt * 16 + hi * 4 + r) * HH + jloc];
    const float bfcv = bfc[0];

    // load base: row j of my tile at ldb + j*1024, lane granule = lane*16
    const size_t ldb = ((size_t)bt * 32) * 1024 + (size_t)lane * 16;
    // store: lane covers row lane>>1, 16B half lane&1 of my 32B col-block
    const size_t sto = ((size_t)(bt * 32 + (lane >> 1))) * 1024
                     + (size_t)wv16 * 32 + (size_t)(lane & 1) * 16;

    char* bA = hbase;                  // buf[s%3]     (read A_s)
    char* bB = hbase + 512 * 1024;     // buf[(s+1)%3] (write A_{s+1})
    char* bC = hbase + 1024 * 1024;    // buf[(s+2)%3] (clear-behind)

    const int swz = l15 & 7;
    const int frow = lane >> 1, fhf = lane & 1, fr7 = frow & 7;  // FC mapping

    for (int s = 0; s <= TT; ++s) {
        if (s == TT && wv16 != 31) break;     // only wave 31 emits y[TT-1]

        // 1. stage A_s [32x512]: 1 instr = 1 full row (64 lanes x 16B);
        //    poll granules until non-sentinel, re-issue only pending rows.
        {
            const char* base = bA + ldb;
            unsigned pend0 = 0xFFFFu, pend1 = 0xFFFFu;
            ull2 q[16];
            for (;;) {
#define LD0(J) if (pend0 & (1u << J)) asm volatile("global_load_dwordx4 %0, %1, off sc0 sc1" : "=v"(q[J]) : "v"(base + J * 1024) : "memory");
#define AC0(J) if ((pend0 & (1u << J)) && !has_sent2(q[J])) { *(ull2*)((char*)Alds + J * 1024 + ((lane ^ (J & 7)) << 4)) = q[J]; pend0 &= ~(1u << J); }
#define LD1(J) if (pend1 & (1u << J)) asm volatile("global_load_dwordx4 %0, %1, off sc0 sc1" : "=v"(q[J]) : "v"(base + (16 + J) * 1024) : "memory");
#define AC1(J) if ((pend1 & (1u << J)) && !has_sent2(q[J])) { *(ull2*)((char*)Alds + (16 + J) * 1024 + ((lane ^ (J & 7)) << 4)) = q[J]; pend1 &= ~(1u << J); }
                if (pend0) {
                    LD0(0) LD0(1) LD0(2) LD0(3) LD0(4) LD0(5) LD0(6) LD0(7)
                    LD0(8) LD0(9) LD0(10) LD0(11) LD0(12) LD0(13) LD0(14) LD0(15)
                    asm volatile("s_waitcnt vmcnt(0)" ::: "memory");
                    __builtin_amdgcn_sched_barrier(0);
                    AC0(0) AC0(1) AC0(2) AC0(3) AC0(4) AC0(5) AC0(6) AC0(7)
                    AC0(8) AC0(9) AC0(10) AC0(11) AC0(12) AC0(13) AC0(14) AC0(15)
                }
                if (pend1) {
                    LD1(0) LD1(1) LD1(2) LD1(3) LD1(4) LD1(5) LD1(6) LD1(7)
                    LD1(8) LD1(9) LD1(10) LD1(11) LD1(12) LD1(13) LD1(14) LD1(15)
                    asm volatile("s_waitcnt vmcnt(0)" ::: "memory");
                    __builtin_amdgcn_sched_barrier(0);
                    AC1(0) AC1(1) AC1(2) AC1(3) AC1(4) AC1(5) AC1(6) AC1(7)
                    AC1(8) AC1(9) AC1(10) AC1(11) AC1(12) AC1(13) AC1(14) AC1(15)
                }
#undef LD0
#undef AC0
#undef LD1
#undef AC1
                if (!(pend0 | pend1)) break;
                __builtin_amdgcn_s_sleep(1);
            }
        }
        // (wave-internal: LDS writes above ordered vs reads below by lgkmcnt)

        // 2. step-0 correction / epilogue FC (wave-local; 2 lanes per row)
        if (s == 0 || s == TT) {
            float x = 0.f;
            #pragma unroll
            for (int u = 0; u < 32; ++u) {
                int g = fhf * 32 + u;
                bf16x8 v = *(const bf16x8*)((char*)Alds + frow * 1024 + ((g ^ fr7) << 4));
                const float* wv = WfcLDS + g * 8;
                #pragma unroll
                for (int e = 0; e < 8; ++e) x += (float)v[e] * wv[e];
            }
            x += __shfl_xor(x, 1);
            if (fhf == 0) {
                if (s == 0) xls[frow] = x + bfcv;
                else out[(size_t)(bt * 32 + frow) * TT + (TT - 1)] = x + bfcv;
            }
            if (s == TT) break;
        }

        // 3. clear-behind: sentinel my 16B granule in buf[(s+2)%3].
        //    Safe: my full A_s staging proves all group waves read h_{s-1}.
        {
            ull2 sv; sv.x = SENT; sv.y = SENT;
            asm volatile("global_store_dwordx4 %0, %1, off sc0 sc1"
                         :: "v"(bC + sto), "v"(sv) : "memory");
        }

        // 4. MFMA: [32,512] @ [512,64]; A swizzled LDS, B regs; gate-major
        f32x4 acc[2][4];
        #pragma unroll
        for (int mt = 0; mt < 2; ++mt)
            #pragma unroll
            for (int g = 0; g < 4; ++g) acc[mt][g] = (f32x4)0.f;

        #pragma unroll
        for (int kk = 0; kk < 16; ++kk) {
            int ch = (((4 * kk + hi) ^ swz) << 4);
            bf16x8 a0 = *(const bf16x8*)((char*)Alds + l15 * 1024 + ch);
            bf16x8 a1 = *(const bf16x8*)((char*)Alds + (l15 + 16) * 1024 + ch);
            #pragma unroll
            for (int g = 0; g < 4; ++g) {
                acc[0][g] = __builtin_amdgcn_mfma_f32_16x16x32_bf16(a0, breg[g][kk], acc[0][g], 0, 0, 0);
                acc[1][g] = __builtin_amdgcn_mfma_f32_16x16x32_bf16(a1, breg[g][kk], acc[1][g], 0, 0, 0);
            }
        }

        // 5. pointwise: fully lane-local (lane has all 4 gates for its
        //    (row,col)); s==0 subtracts the x0c*Wih correction (x_0 = 0).
        #pragma unroll
        for (int mt = 0; mt < 2; ++mt)
            #pragma unroll
            for (int r = 0; r < 4; ++r) {
                int lrow = mt * 16 + hi * 4 + r;
                float xc = (s == 0) ? xls[lrow] : 0.f;
                float xi = acc[mt][0][r] + biasr[0] - xc * wihr[0];
                float xf = acc[mt][1][r] + biasr[1] - xc * wihr[1];
                float xg = acc[mt][2][r] + biasr[2] - xc * wihr[2];
                float xo = acc[mt][3][r] + biasr[3] - xc * wihr[3];
                float si = sigmoid_fast(xi), sf = sigmoid_fast(xf), so = sigmoid_fast(xo);
                float tg = tanh_fast(xg);
                float cn = sf * creg[mt][r] + si * tg;
                creg[mt][r] = cn;
                hrep[lrow][l15] = (bf16)(so * tanh_fast(cn));
            }

        // 6. repack via wave-local LDS, store 16B granule (no vmcnt: the
        //    clear of this buffer (step s-1) drained at staging's vmcnt(0)).
        {
            ull2 hv = *(const ull2*)((char*)hrep + (lane >> 1) * 32 + (lane & 1) * 16);
            asm volatile("global_store_dwordx4 %0, %1, off sc0 sc1"
                         :: "v"(bB + sto), "v"(hv) : "memory");
        }

        // 7. y-output FC, round-robin: wave wv16 emits y[:, s-1] when
        //    (s-1)&31 == wv16. Wave-local LDS reads, off the critical path.
        if (s > 0 && ((s - 1) & 31) == wv16) {
            float x = 0.f;
            #pragma unroll
            for (int u = 0; u < 32; ++u) {
                int g = fhf * 32 + u;
                bf16x8 v = *(const bf16x8*)((char*)Alds + frow * 1024 + ((g ^ fr7) << 4));
                const float* wv = WfcLDS + g * 8;
                #pragma unroll
                for (int e = 0; e < 8; ++e) x += (float)v[e] * wv[e];
            }
            x += __shfl_xor(x, 1);
            if (fhf == 0)
                out[(size_t)(bt * 32 + frow) * TT + (s - 1)] = x + bfcv;
        }

        // rotate buffers: (A,B,C) <- (B,C,A)
        char* t = bA; bA = bB; bB = bC; bC = t;
    }
}

extern "C" void kernel_launch(void* const* d_in, const int* in_sizes, int n_in,
                              void* d_out, int out_size, void* d_ws, size_t ws_size,
                              hipStream_t stream) {
    const float* h   = (const float*)d_in[0];
    const float* c   = (const float*)d_in[1];
    const float* Wih = (const float*)d_in[2];
    const float* Whh = (const float*)d_in[3];
    const float* bih = (const float*)d_in[4];
    const float* bhh = (const float*)d_in[5];
    const float* Wfc = (const float*)d_in[6];
    const float* bfc = (const float*)d_in[7];
    float* out = (float*)d_out;

    char* ws = (char*)d_ws;
    bf16*  WcT   = (bf16*)(ws + WT_OFF);
    float* biasC = (float*)(ws + BC_OFF);
    char*  hb    = ws + H0_OFF;

    prep_weights<<<2048, 256, 0, stream>>>(Whh, Wih, bih, bhh, Wfc, bfc, WcT, biasC);
    prep_state<<<1024, 256, 0, stream>>>(h, (bf16*)hb,
        (unsigned short*)(hb + 512 * 1024), (unsigned short*)(hb + 1024 * 1024));
    lstm_persist<<<512, 64, 0, stream>>>(WcT, biasC, Wih, Wfc, bfc, c, hb, out);
}

// Round 14
// 3483.215 us; speedup vs baseline: 3.2958x; 3.2958x over previous
//
#include <hip/hip_runtime.h>
#include <hip/hip_bf16.h>
#include <math.h>

#define BB 512
#define HH 512
#define TT 1024
#define BUFSZ (512*1024)

typedef __bf16 bf16;
typedef __bf16 bf16x8 __attribute__((ext_vector_type(8)));
typedef float f32x4 __attribute__((ext_vector_type(4)));
typedef unsigned long long ull;
typedef ull ull2 __attribute__((ext_vector_type(2)));

// ---------------- ws layout (bytes) ----------------
// WcT : [2048][512] bf16 @ 0      (2 MB)  folded: Whh + Wfc ⊗ Wih
// biasC: [2048] f32      @ 2 MB   (8 KB)
// hb0/1: [512][512] bf16 double-buffered h (2 x 512 KB)
// flags: [16*32] int (128B-spaced groups of 16 producer epoch slots)
#define WT_OFF 0
#define BC_OFF (2*1024*1024)
#define H0_OFF (BC_OFF + 8192)
#define FL_OFF (H0_OFF + 2*BUFSZ)

__global__ void prep_weights(const float* __restrict__ Whh, const float* __restrict__ Wih,
                             const float* __restrict__ bih, const float* __restrict__ bhh,
                             const float* __restrict__ Wfc, const float* __restrict__ bfc,
                             bf16* __restrict__ WcT, float* __restrict__ biasC) {
    int col = blockIdx.x;                 // 0..2047
    float wih = Wih[col];
    for (int k = threadIdx.x; k < HH; k += blockDim.x)
        WcT[col * HH + k] = (bf16)(Whh[col * HH + k] + Wfc[k] * wih);
    if (threadIdx.x == 0) biasC[col] = bih[col] + bhh[col] + bfc[0] * wih;
}

__global__ void prep_state(const float* __restrict__ h, bf16* __restrict__ h0buf,
                           int* __restrict__ flags) {
    int i = blockIdx.x * blockDim.x + threadIdx.x;
    if (i < BB * HH) h0buf[i] = (bf16)h[i];
    if (i < 16 * 32) flags[i] = 0;
}

__device__ __forceinline__ float tanh_fast(float x) {
    float ax = fabsf(x);
    float e = __expf(-2.f * ax);
    float r = (1.f - e) / (1.f + e);
    return copysignf(r, x);
}
__device__ __forceinline__ float sigmoid_fast(float x) {
    return 1.f / (1.f + __expf(-x));
}

// Persistent LSTM. Sync = per-producer epoch flags (detect, 64B/wave/sweep)
// + ONE coalesced data sweep (transfer), both via the MALL (sc0 sc1 — the
// only validated inter-wg path). vs r12: poll traffic /128 (r12's limiter:
// sentinel sweeps re-read 8KB/wave and congest the MALL), data read once,
// no sentinels / no clear-behind / 2 buffers (flag s+1 from all members
// proves their A_{s-1} reads retired => overwrite-safe). Producer publish:
// data stores -> __syncthreads() (per-thread vmcnt(0) drain) -> plain
// relaxed SYSTEM flag store (no RMW, no wbl2) — r4-proven.
__global__ __launch_bounds__(256, 1) void lstm_persist(
    const bf16* __restrict__ WcT,     // [2048][512] bf16 (folded)
    const float* __restrict__ biasC,  // [2048]
    const float* __restrict__ Wih,    // [2048]
    const float* __restrict__ Wfc,    // [512]
    const float* __restrict__ bfc,    // [1]
    const float* __restrict__ c0,     // [512*512] f32
    char* __restrict__ hbase,         // 2 x 512KB buffers
    int* __restrict__ flags,          // [16*32]
    float* __restrict__ out)          // [512][1024]
{
    __shared__ __align__(16) bf16 Alds[32 * 512];  // XOR-swizzled h tile (32 KB)
    __shared__ float xls[32];                      // step-0 correction per row
    __shared__ float WfcLDS[512];
    __shared__ bf16 hrep[32][40];                  // h repack for coalesced stores

    const int tid  = threadIdx.x;
    const int wave = tid >> 6;
    const int lane = tid & 63;
    const int l15  = lane & 15;
    const int hi   = lane >> 4;
    const int xcd = blockIdx.x & 7;
    const int ii  = blockIdx.x >> 3;
    const int bt  = xcd * 2 + (ii & 1);       // 0..15
    const int hs  = ii >> 1;                  // 0..15

    WfcLDS[tid] = Wfc[tid];
    WfcLDS[tid + 256] = Wfc[tid + 256];

    bf16x8 breg[2][16];
    float biasr[2], wihr[2];
    #pragma unroll
    for (int nt = 0; nt < 2; ++nt) {
        int gcol = (nt * 2 + (l15 >> 3)) * HH + hs * 32 + wave * 8 + (l15 & 7);
        const bf16* wp = WcT + (size_t)gcol * HH + hi * 8;
        #pragma unroll
        for (int kk = 0; kk < 16; ++kk)
            breg[nt][kk] = *(const bf16x8*)(wp + kk * 32);
        biasr[nt] = biasC[gcol];
        wihr[nt]  = Wih[gcol];
    }
    const bool lo = (l15 < 8);
    float p0 = __shfl_xor(biasr[0], 8), p1 = __shfl_xor(biasr[1], 8);
    const float bI = lo ? biasr[0] : p0, bF = lo ? p0 : biasr[0];
    const float bG = lo ? biasr[1] : p1, bO = lo ? p1 : biasr[1];
    p0 = __shfl_xor(wihr[0], 8); p1 = __shfl_xor(wihr[1], 8);
    const float wI = lo ? wihr[0] : p0, wF = lo ? p0 : wihr[0];
    const float wG = lo ? wihr[1] : p1, wO = lo ? p1 : wihr[1];

    const int mymt = lo ? 0 : 1;
    const int jcol = wave * 8 + (l15 & 7);
    const int jloc = hs * 32 + jcol;
    float creg[4];
    #pragma unroll
    for (int r = 0; r < 4; ++r) {
        int brow = bt * 32 + mymt * 16 + hi * 4 + r;
        creg[r] = c0[(size_t)brow * HH + jloc];
    }
    const float bfcv = bfc[0];

    const int swz = l15 & 7;
    const int row = tid >> 3;
    const int seg = tid & 7;
    const int r7  = row & 7;

    int* myslots = flags + bt * 32;
    int* myslot  = myslots + hs;

    const size_t grp = ((size_t)(bt * 32 + wave * 8)) * 1024 + (size_t)lane * 16;
    const size_t sto = ((size_t)(bt * 32 + row)) * 1024 + (size_t)hs * 64 + (size_t)seg * 8;
    char* aldsW = (char*)Alds + wave * 8 * 1024;

    __syncthreads();

    for (int s = 0; s <= TT; ++s) {
        if (s == TT && hs != 0) break;

        // 1. detect: 16 lanes poll the group's epoch slots (64B per sweep)
        if (lane < 16) {
            while (__hip_atomic_load(myslots + lane, __ATOMIC_RELAXED,
                                     __HIP_MEMORY_SCOPE_SYSTEM) < s)
                __builtin_amdgcn_s_sleep(1);
        }

        // 2. stage A_s: ONE coalesced sweep (8 x 1KB rows), swizzled LDS
        {
            const char* blo = hbase + (size_t)(s & 1) * BUFSZ + grp;
            const char* bhi = blo + 4096;
            ull2 q0, q1, q2, q3, q4, q5, q6, q7;
            asm volatile(
                "global_load_dwordx4 %0, %8, off sc0 sc1\n\t"
                "global_load_dwordx4 %1, %8, off offset:1024 sc0 sc1\n\t"
                "global_load_dwordx4 %2, %8, off offset:2048 sc0 sc1\n\t"
                "global_load_dwordx4 %3, %8, off offset:3072 sc0 sc1\n\t"
                "global_load_dwordx4 %4, %9, off sc0 sc1\n\t"
                "global_load_dwordx4 %5, %9, off offset:1024 sc0 sc1\n\t"
                "global_load_dwordx4 %6, %9, off offset:2048 sc0 sc1\n\t"
                "global_load_dwordx4 %7, %9, off offset:3072 sc0 sc1\n\t"
                "s_waitcnt vmcnt(0)"
                : "=&v"(q0), "=&v"(q1), "=&v"(q2), "=&v"(q3),
                  "=&v"(q4), "=&v"(q5), "=&v"(q6), "=&v"(q7)
                : "v"(blo), "v"(bhi) : "memory");
            __builtin_amdgcn_sched_barrier(0);
            *(ull2*)(aldsW            + ((lane ^ 0) << 4)) = q0;
            *(ull2*)(aldsW + 1 * 1024 + ((lane ^ 1) << 4)) = q1;
            *(ull2*)(aldsW + 2 * 1024 + ((lane ^ 2) << 4)) = q2;
            *(ull2*)(aldsW + 3 * 1024 + ((lane ^ 3) << 4)) = q3;
            *(ull2*)(aldsW + 4 * 1024 + ((lane ^ 4) << 4)) = q4;
            *(ull2*)(aldsW + 5 * 1024 + ((lane ^ 5) << 4)) = q5;
            *(ull2*)(aldsW + 6 * 1024 + ((lane ^ 6) << 4)) = q6;
            *(ull2*)(aldsW + 7 * 1024 + ((lane ^ 7) << 4)) = q7;
        }
        __syncthreads();

        // LDS granule map: row r, 16B-granule g at r*1024 + ((g ^ (r&7))<<4).
        // FC reads (granule g = cc*16B where cc indexes 8-bf16 chunks):
        if (s == 0 || s == TT) {
            float xacc = 0.f;
            const char* arow = (char*)Alds + row * 1024;
            #pragma unroll
            for (int u = 0; u < 8; ++u) {
                int cc = seg * 8 + u;
                bf16x8 v = *(const bf16x8*)(arow + (((cc ^ r7) & 63) << 4));
                const float* wv = WfcLDS + cc * 8;
                #pragma unroll
                for (int e = 0; e < 8; ++e) xacc += (float)v[e] * wv[e];
            }
            xacc += __shfl_xor(xacc, 1);
            xacc += __shfl_xor(xacc, 2);
            xacc += __shfl_xor(xacc, 4);
            xacc += bfcv;
            if (seg == 0) {
                if (s == 0) xls[row] = xacc;
                else out[((size_t)(bt * 32 + row)) * TT + (TT - 1)] = xacc;
            }
            if (s == TT) break;
        }

        // 4. MFMA (granule index (hi + 4*kk) ^ swz, identical bytes to r12)
        f32x4 acc[2][2];
        #pragma unroll
        for (int i = 0; i < 2; ++i)
            #pragma unroll
            for (int j = 0; j < 2; ++j) acc[i][j] = (f32x4)0.f;

        #pragma unroll
        for (int kk = 0; kk < 16; ++kk) {
            int g = (hi + 4 * kk) ^ swz;
            bf16x8 a0 = *(const bf16x8*)((char*)Alds + l15 * 1024 + (g << 4));
            bf16x8 a1 = *(const bf16x8*)((char*)Alds + (l15 + 16) * 1024 + (g << 4));
            acc[0][0] = __builtin_amdgcn_mfma_f32_16x16x32_bf16(a0, breg[0][kk], acc[0][0], 0, 0, 0);
            acc[0][1] = __builtin_amdgcn_mfma_f32_16x16x32_bf16(a0, breg[1][kk], acc[0][1], 0, 0, 0);
            acc[1][0] = __builtin_amdgcn_mfma_f32_16x16x32_bf16(a1, breg[0][kk], acc[1][0], 0, 0, 0);
            acc[1][1] = __builtin_amdgcn_mfma_f32_16x16x32_bf16(a1, breg[1][kk], acc[1][1], 0, 0, 0);
        }

        if (s == 0) __syncthreads();

        // 5. pointwise
        #pragma unroll
        for (int r = 0; r < 4; ++r) {
            float send0 = lo ? acc[1][0][r] : acc[0][0][r];
            float send1 = lo ? acc[1][1][r] : acc[0][1][r];
            float recv0 = __shfl_xor(send0, 8);
            float recv1 = __shfl_xor(send1, 8);
            float own0  = lo ? acc[0][0][r] : acc[1][0][r];
            float own1  = lo ? acc[0][1][r] : acc[1][1][r];
            int  lrow = mymt * 16 + hi * 4 + r;
            float xc = (s == 0) ? xls[lrow] : 0.f;
            float xi = (lo ? own0 : recv0) + bI - xc * wI;
            float xf = (lo ? recv0 : own0) + bF - xc * wF;
            float xg = (lo ? own1 : recv1) + bG - xc * wG;
            float xo = (lo ? recv1 : own1) + bO - xc * wO;
            float si = sigmoid_fast(xi), sf = sigmoid_fast(xf), so = sigmoid_fast(xo);
            float tg = tanh_fast(xg);
            float cn = sf * creg[r] + si * tg;
            creg[r] = cn;
            hrep[lrow][jcol] = (bf16)(so * tanh_fast(cn));
        }
        __syncthreads();

        // 6. store A_{s+1} into buf[(s+1)&1]
        {
            ull val = *(const ull*)&hrep[row][seg * 4];
            char* stp = hbase + (size_t)((s + 1) & 1) * BUFSZ + sto;
            asm volatile("global_store_dwordx2 %0, %1, off sc0 sc1"
                         :: "v"(stp), "v"(val) : "memory");
        }
        __syncthreads();   // per-thread vmcnt(0) drain: all stores at MALL

        // 7. publish epoch
        if (tid == 0)
            __hip_atomic_store(myslot, s + 1, __ATOMIC_RELAXED,
                               __HIP_MEMORY_SCOPE_SYSTEM);

        // 8. round-robin y FC (off critical path)
        if (s > 0 && (s & 15) == hs) {
            float xacc = 0.f;
            const char* arow = (char*)Alds + row * 1024;
            #pragma unroll
            for (int u = 0; u < 8; ++u) {
                int cc = seg * 8 + u;
                bf16x8 v = *(const bf16x8*)(arow + (((cc ^ r7) & 63) << 4));
                const float* wv = WfcLDS + cc * 8;
                #pragma unroll
                for (int e = 0; e < 8; ++e) xacc += (float)v[e] * wv[e];
            }
            xacc += __shfl_xor(xacc, 1);
            xacc += __shfl_xor(xacc, 2);
            xacc += __shfl_xor(xacc, 4);
            if (seg == 0)
                out[((size_t)(bt * 32 + row)) * TT + (s - 1)] = xacc + bfcv;
        }
    }
}

extern "C" void kernel_launch(void* const* d_in, const int* in_sizes, int n_in,
                              void* d_out, int out_size, void* d_ws, size_t ws_size,
                              hipStream_t stream) {
    const float* h   = (const float*)d_in[0];
    const float* c   = (const float*)d_in[1];
    const float* Wih = (const float*)d_in[2];
    const float* Whh = (const float*)d_in[3];
    const float* bih = (const float*)d_in[4];
    const float* bhh = (const float*)d_in[5];
    const float* Wfc = (const float*)d_in[6];
    const float* bfc = (const float*)d_in[7];
    float* out = (float*)d_out;

    char* ws = (char*)d_ws;
    bf16*  WcT   = (bf16*)(ws + WT_OFF);
    float* biasC = (float*)(ws + BC_OFF);
    char*  hb    = ws + H0_OFF;
    int*   flags = (int*)(ws + FL_OFF);

    prep_weights<<<2048, 256, 0, stream>>>(Whh, Wih, bih, bhh, Wfc, bfc, WcT, biasC);
    prep_state<<<1024, 256, 0, stream>>>(h, (bf16*)hb, flags);
    lstm_persist<<<256, 256, 0, stream>>>(WcT, biasC, Wih, Wfc, bfc, c, hb, flags, out);
}